// Round 8
// baseline (301.107 us; speedup 1.0000x reference)
//
#include <hip/hip_runtime.h>

#define Bz 8
#define Sz 2048
#define Ez 512
#define Hz 8
#define Dz 64
#define VTR 80   // compacted V^T rows: 64 d + indicator + 15 zero

typedef _Float16 f16;
typedef __attribute__((ext_vector_type(2))) _Float16 f16x2;
typedef __attribute__((ext_vector_type(8))) _Float16 f16x8;
typedef __attribute__((ext_vector_type(4))) float f32x4;

#define LOG2E 1.44269504f

__device__ __forceinline__ void async16(const void* g, void* l) {
    __builtin_amdgcn_global_load_lds(
        (const __attribute__((address_space(1))) unsigned int*)g,
        (__attribute__((address_space(3))) unsigned int*)l, 16, 0, 0);
}

__device__ __forceinline__ f16x2 pkrtz(float a, float b) {
    return __builtin_bit_cast(f16x2, __builtin_amdgcn_cvt_pkrtz(a, b));
}

__device__ __forceinline__ int swz(int row) {
    return (row & 7) ^ ((2 * ((row >> 3) & 3)) & 7);
}

// ===========================================================================
// cast: fp32 activations -> f16 (z picks q/k/v)
// ===========================================================================
__global__ __launch_bounds__(256)
void cast_kernel(const float* __restrict__ q, const float* __restrict__ k,
                 const float* __restrict__ v,
                 f16* __restrict__ qa, f16* __restrict__ ka, f16* __restrict__ va)
{
    const int z = blockIdx.y;
    const int idx = blockIdx.x * 256 + threadIdx.x;
    const float* src = (z == 0) ? q : (z == 1) ? k : v;
    f16* dst = (z == 0) ? qa : (z == 1) ? ka : va;
    float4 x = *(const float4*)&src[(size_t)idx * 4];
    f16x2 h0 = pkrtz(x.x, x.y), h1 = pkrtz(x.z, x.w);
    f16 h[4] = {h0[0], h0[1], h1[0], h1[1]};
    *(uint2*)&dst[(size_t)idx * 4] = *(uint2*)h;
}

// ===========================================================================
// prep_w: W fp32 [k][n] -> Wt f16 [n][k]; z==0 (wq) scaled by 0.125*log2e
// ===========================================================================
__global__ __launch_bounds__(256)
void prep_w(const float* __restrict__ W0, const float* __restrict__ W1,
            const float* __restrict__ W2, const float* __restrict__ W3,
            f16* __restrict__ T0, f16* __restrict__ T1,
            f16* __restrict__ T2, f16* __restrict__ T3)
{
    __shared__ float S[64][68];
    const float* W = (blockIdx.z==0)?W0:(blockIdx.z==1)?W1:(blockIdx.z==2)?W2:W3;
    f16*         T = (blockIdx.z==0)?T0:(blockIdx.z==1)?T1:(blockIdx.z==2)?T2:T3;
    const float sc = (blockIdx.z == 0) ? 0.125f * LOG2E : 1.0f;
    const int k0 = blockIdx.x * 64, n0 = blockIdx.y * 64;
    const int tid = threadIdx.x;
    {
        int kr = tid >> 4, nc = (tid & 15) * 4;
        #pragma unroll
        for (int i = 0; i < 4; ++i) {
            float4 w4 = *(const float4*)&W[(size_t)(k0 + kr + i*16) * Ez + n0 + nc];
            S[kr + i*16][nc+0] = w4.x; S[kr + i*16][nc+1] = w4.y;
            S[kr + i*16][nc+2] = w4.z; S[kr + i*16][nc+3] = w4.w;
        }
    }
    __syncthreads();
    {
        int n = tid >> 2, kq = tid & 3;
        f16 h[16];
        #pragma unroll
        for (int j = 0; j < 16; ++j) h[j] = (f16)(S[kq*16 + j][n] * sc);
        f16* dst = &T[(size_t)(n0 + n) * Ez + k0 + kq*16];
        *(uint4*)&dst[0] = *(uint4*)&h[0];
        *(uint4*)&dst[8] = *(uint4*)&h[8];
    }
}

// ===========================================================================
// mask_index: per batch, compact list of UNMASKED key indices + slen.
// ===========================================================================
__global__ __launch_bounds__(256)
void mask_index(const int* __restrict__ mask, int* __restrict__ idx,
                int* __restrict__ slen)
{
    __shared__ int sc2[2][256];
    __shared__ int stot;
    const int b = blockIdx.x, tid = threadIdx.x;
    const int* mp = mask + (size_t)b * Sz;
    int m[8], c = 0;
    #pragma unroll
    for (int j = 0; j < 8; ++j) { m[j] = mp[tid*8 + j]; c += (m[j] == 0); }
    sc2[0][tid] = c;
    __syncthreads();
    int src = 0;
    #pragma unroll
    for (int s = 1; s < 256; s <<= 1) {
        int v = sc2[src][tid] + ((tid >= s) ? sc2[src][tid - s] : 0);
        sc2[src ^ 1][tid] = v;
        src ^= 1;
        __syncthreads();
    }
    int incl = sc2[src][tid];
    int base = incl - c;
    if (tid == 255) { slen[b] = incl; stot = incl; }
    int k = base;
    #pragma unroll
    for (int j = 0; j < 8; ++j)
        if (m[j] == 0) idx[(size_t)b * Sz + (k++)] = tid*8 + j;
    __syncthreads();
    for (int j = stot + tid; j < Sz; j += 256) idx[(size_t)b * Sz + j] = 0;
}

// ===========================================================================
// compact_v: gather unmasked V rows, transpose to (B,H,VTR,Sz) compacted.
// Row 64 = validity indicator (1/0); rows 65..79 = 0.
// ===========================================================================
__global__ __launch_bounds__(256)
void compact_v(const f16* __restrict__ vp, const int* __restrict__ idx,
               const int* __restrict__ slen, f16* __restrict__ vt)
{
    const int ct = blockIdx.x, h = blockIdx.y, b = blockIdx.z;
    const int sl = slen[b];
    if (ct * 64 >= sl && !(ct == 0 && sl == 0)) return;
    __shared__ f16 S[64 * 72];
    const int tid = threadIdx.x;
    {
        int r = tid >> 2, ch = tid & 3;
        int j = ct * 64 + r;
        uint4 v0 = {0,0,0,0}, v1 = {0,0,0,0};
        if (j < sl) {
            int s = idx[(size_t)b * Sz + j];
            const f16* srcp = vp + (((size_t)b * Hz + h) * Sz + s) * Dz + ch * 16;
            v0 = *(const uint4*)&srcp[0];
            v1 = *(const uint4*)&srcp[8];
        }
        *(uint4*)&S[r*72 + ch*16]     = v0;
        *(uint4*)&S[r*72 + ch*16 + 8] = v1;
    }
    __syncthreads();
    f16* base = vt + ((size_t)b * Hz + h) * VTR * Sz;
    {
        int d = tid >> 2, kq = tid & 3;
        f16 hh[16];
        #pragma unroll
        for (int j = 0; j < 16; ++j) hh[j] = S[(kq*16 + j)*72 + d];
        f16* dst = base + (size_t)d * Sz + ct*64 + kq*16;
        *(uint4*)&dst[0] = *(uint4*)&hh[0];
        *(uint4*)&dst[8] = *(uint4*)&hh[8];
    }
    // rows 64..79: indicator + zeros
    if (tid < 128) {
        int row = 64 + (tid >> 3);
        int c0 = (tid & 7) * 8;
        f16 hh[8];
        #pragma unroll
        for (int j = 0; j < 8; ++j)
            hh[j] = (row == 64 && (ct*64 + c0 + j) < sl) ? (f16)1.0f : (f16)0.0f;
        *(uint4*)&base[(size_t)row * Sz + ct*64 + c0] = *(uint4*)hh;
    }
}

// ===========================================================================
// proj_gemm: single-buffer DMA staging, 128x128 tile, BK=32 (unchanged R7).
// ===========================================================================
__global__ __launch_bounds__(256, 4)
void proj_gemm(const f16* __restrict__ qa, const f16* __restrict__ ka,
               const f16* __restrict__ va,
               const f16* __restrict__ wtq, const f16* __restrict__ wtk,
               const f16* __restrict__ wtv,
               const float* __restrict__ bqp, const float* __restrict__ bkp,
               const float* __restrict__ bvp,
               f16* __restrict__ qp, f16* __restrict__ kp, f16* __restrict__ vp)
{
    __shared__ __align__(16) char lds[18432];
    const int z = blockIdx.z;
    const f16* A  = (z==0)?qa:(z==1)?ka:va;
    const f16* Wt = (z==0)?wtq:(z==1)?wtk:wtv;
    const float* bias = (z==0)?bqp:(z==1)?bkp:bvp;
    f16* C16 = (z==0)?qp:(z==1)?kp:vp;
    const float bscale = (z==0) ? 0.125f*LOG2E : 1.0f;

    const int tid  = threadIdx.x;
    const int lane = tid & 63, w = tid >> 6;
    const int col  = lane & 15, quad = lane >> 4;
    const int wm = w & 1, wn = w >> 1;
    const int m0 = blockIdx.x * 128, n0 = blockIdx.y * 128;
    const int srow = lane >> 2, schunk = lane & 3;

    f16* As = (f16*)lds;
    f16* Ws = As + 4096;

    f32x4 acc[4][4];
    #pragma unroll
    for (int i = 0; i < 4; ++i)
        #pragma unroll
        for (int j = 0; j < 4; ++j) acc[i][j] = (f32x4){0.f,0.f,0.f,0.f};

    const int xrc = (col >> 1) & 3;

    for (int t = 0; t < 16; ++t) {
        __syncthreads();
        #pragma unroll
        for (int i = 0; i < 2; ++i) {
            int row = w*32 + i*16 + srow;
            int cl = schunk ^ ((row >> 1) & 3);
            async16(&A[(size_t)(m0 + row) * Ez + t*32 + cl*8],  &As[row*32 + schunk*8]);
            async16(&Wt[(size_t)(n0 + row) * Ez + t*32 + cl*8], &Ws[row*32 + schunk*8]);
        }
        __syncthreads();
        f16x8 af[4];
        #pragma unroll
        for (int mi = 0; mi < 4; ++mi)
            af[mi] = *(const f16x8*)&As[(wm*64 + mi*16 + col)*32 + ((quad ^ xrc)*8)];
        #pragma unroll
        for (int ni = 0; ni < 4; ++ni) {
            f16x8 wf = *(const f16x8*)&Ws[(wn*64 + ni*16 + col)*32 + ((quad ^ xrc)*8)];
            #pragma unroll
            for (int mi = 0; mi < 4; ++mi)
                acc[mi][ni] = __builtin_amdgcn_mfma_f32_16x16x32_f16(af[mi], wf, acc[mi][ni], 0,0,0);
        }
    }

    f16* Tr = (f16*)lds;     // [128][72]
    #pragma unroll
    for (int p = 0; p < 2; ++p) {
        __syncthreads();
        if (wn == p) {
            #pragma unroll
            for (int ni = 0; ni < 4; ++ni) {
                float bv = bias[n0 + p*64 + ni*16 + col] * bscale;
                #pragma unroll
                for (int mi = 0; mi < 4; ++mi)
                    #pragma unroll
                    for (int rr = 0; rr < 4; ++rr) {
                        int ml = wm*64 + mi*16 + quad*4 + rr;
                        Tr[ml*72 + ni*16 + col] = (f16)(acc[mi][ni][rr] + bv);
                    }
            }
        }
        __syncthreads();
        int rw = tid >> 1, half = tid & 1;
        int m = m0 + rw, b = m >> 11, s = m & (Sz-1);
        int hh = (n0 >> 6) + p;
        f16* dst = &C16[(((size_t)b*Hz + hh)*Sz + s)*Dz + half*32];
        const f16* srcp = &Tr[rw*72 + half*32];
        #pragma unroll
        for (int j = 0; j < 4; ++j)
            *(uint4*)&dst[j*8] = *(const uint4*)&srcp[j*8];
    }
}

// ===========================================================================
// out_gemm: 128x64 tile (1024 blocks -> 4 blocks/CU), single-buffer staging.
// ===========================================================================
__global__ __launch_bounds__(256, 4)
void out_gemm(const f16* __restrict__ A, const f16* __restrict__ Wt,
              const float* __restrict__ bias, float* __restrict__ Cf)
{
    __shared__ __align__(16) f16 smem[6144];   // A 128x32 + W 64x32
    f16* As = smem;
    f16* Ws = smem + 4096;

    const int tid  = threadIdx.x;
    const int lane = tid & 63, w = tid >> 6;
    const int col  = lane & 15, quad = lane >> 4;
    const int m0 = blockIdx.x * 128, n0 = blockIdx.y * 64;

    f32x4 acc[2][4];
    #pragma unroll
    for (int i = 0; i < 2; ++i)
        #pragma unroll
        for (int j = 0; j < 4; ++j) acc[i][j] = (f32x4){0.f,0.f,0.f,0.f};

    const int xrc = (col >> 1) & 3;

    for (int t = 0; t < 16; ++t) {
        __syncthreads();
        #pragma unroll
        for (int i = 0; i < 2; ++i) {
            int row = i*64 + (tid >> 2);
            int ch = tid & 3;
            int cl = ch ^ ((row >> 1) & 3);
            async16(&A[(size_t)(m0 + row) * Ez + t*32 + cl*8], &As[row*32 + ch*8]);
        }
        {
            int row = tid >> 2;
            int ch = tid & 3;
            int cl = ch ^ ((row >> 1) & 3);
            async16(&Wt[(size_t)(n0 + row) * Ez + t*32 + cl*8], &Ws[row*32 + ch*8]);
        }
        __syncthreads();
        f16x8 af[2];
        #pragma unroll
        for (int mi = 0; mi < 2; ++mi)
            af[mi] = *(const f16x8*)&As[(w*32 + mi*16 + col)*32 + ((quad ^ xrc)*8)];
        #pragma unroll
        for (int ni = 0; ni < 4; ++ni) {
            f16x8 wf = *(const f16x8*)&Ws[(ni*16 + col)*32 + ((quad ^ xrc)*8)];
            #pragma unroll
            for (int mi = 0; mi < 2; ++mi)
                acc[mi][ni] = __builtin_amdgcn_mfma_f32_16x16x32_f16(af[mi], wf, acc[mi][ni], 0,0,0);
        }
    }

    #pragma unroll
    for (int ni = 0; ni < 4; ++ni) {
        int n = n0 + ni*16 + col;
        float bv = bias[n];
        #pragma unroll
        for (int mi = 0; mi < 2; ++mi)
            #pragma unroll
            for (int rr = 0; rr < 4; ++rr) {
                int m = m0 + w*32 + mi*16 + quad*4 + rr;
                Cf[(size_t)m * Ez + n] = acc[mi][ni][rr] + bv;
            }
    }
}

// ===========================================================================
// Flash attention over compacted keys. lsum computed by indicator-row MFMA
// (V^T row 64 = validity), eliminating per-lane lsum adds + tail predication.
// ===========================================================================
__global__ __launch_bounds__(256, 4)
void attn_f16(const f16* __restrict__ Q, const f16* __restrict__ K,
              const f16* __restrict__ VT, const int* __restrict__ idx,
              const int* __restrict__ slen, f16* __restrict__ O)
{
    __shared__ __align__(16) f16 KS[2][64*64];
    __shared__ __align__(16) f16 VS[2][VTR*64];

    const int tid  = threadIdx.x;
    const int lane = tid & 63, w = tid >> 6;
    const int col  = lane & 15, quad = lane >> 4;

    const int blk = blockIdx.x;
    const int xcd = blk & 7, slot = blk >> 3;
    const int bh = xcd + 8 * (slot >> 4);
    const int qb = slot & 15;
    const int b = bh >> 3, h = bh & 7;

    const int sl = slen[b];
    int nt = (sl + 63) >> 6;
    if (nt < 1) nt = 1;

    const int q0 = qb * 128 + w * 32;

    f16x8 qf[2][2];
    #pragma unroll
    for (int qt = 0; qt < 2; ++qt)
        #pragma unroll
        for (int ks = 0; ks < 2; ++ks)
            qf[qt][ks] = *(const f16x8*)&Q[((size_t)bh*Sz + q0 + qt*16 + col)*Dz + ks*32 + quad*8];

    const f16* Kp = K + (size_t)bh * Sz * Dz;
    const f16* Vp = VT + (size_t)bh * VTR * Sz;
    const int* ixp = idx + (size_t)b * Sz;

    const int srow = lane >> 3, sch = lane & 7;
    const int row0 = w*16 + srow, row1 = row0 + 8;
    const int cl0 = sch ^ swz(row0), cl1 = sch ^ swz(row1);
    const int rowe = 64 + 8*w + srow;              // extra V rows (waves 0,1)
    const int cle = sch ^ swz(rowe);

    int keyrow[4], gk[4];
    #pragma unroll
    for (int kc = 0; kc < 4; ++kc) {
        keyrow[kc] = 32*(kc>>1) + 8*(col>>2) + 4*(kc&1) + (col&3);
        gk[kc] = swz(keyrow[kc]);
    }
    const int rowo = 64 + col;                     // ones/indicator A-frag row
    const int go = swz(rowo);

    f32x4 oacc[2][4];
    #pragma unroll
    for (int qt = 0; qt < 2; ++qt)
        #pragma unroll
        for (int dc = 0; dc < 4; ++dc) oacc[qt][dc] = (f32x4){0.f,0.f,0.f,0.f};
    f32x4 lsacc[2] = {(f32x4){0.f,0.f,0.f,0.f}, (f32x4){0.f,0.f,0.f,0.f}};

    auto issue = [&](int t, int buf, int s0, int s1) {
        async16(&Kp[(size_t)s0*Dz + cl0*8],          &KS[buf][row0*64 + sch*8]);
        async16(&Vp[(size_t)row0*Sz + t*64 + cl0*8], &VS[buf][row0*64 + sch*8]);
        async16(&Kp[(size_t)s1*Dz + cl1*8],          &KS[buf][row1*64 + sch*8]);
        async16(&Vp[(size_t)row1*Sz + t*64 + cl1*8], &VS[buf][row1*64 + sch*8]);
        if (w < 2)
            async16(&Vp[(size_t)rowe*Sz + t*64 + cle*8], &VS[buf][rowe*64 + sch*8]);
    };

    int cs0 = ixp[row0], cs1 = ixp[row1];
    issue(0, 0, cs0, cs1);
    int ns0 = 0, ns1 = 0;
    if (nt > 1) { ns0 = ixp[64 + row0]; ns1 = ixp[64 + row1]; }

    for (int t = 0; t < nt; ++t) {
        const int cur = t & 1;
        __syncthreads();
        if (t + 1 < nt) {
            issue(t + 1, cur ^ 1, ns0, ns1);
            if (t + 2 < nt) {
                ns0 = ixp[(t+2)*64 + row0];
                ns1 = ixp[(t+2)*64 + row1];
            }
        }

        // ---- QK^T: S^T = K·Q^T
        f32x4 sc[2][4];
        #pragma unroll
        for (int qt = 0; qt < 2; ++qt)
            #pragma unroll
            for (int kc = 0; kc < 4; ++kc) sc[qt][kc] = (f32x4){0.f,0.f,0.f,0.f};
        #pragma unroll
        for (int kc = 0; kc < 4; ++kc) {
            #pragma unroll
            for (int ks = 0; ks < 2; ++ks) {
                f16x8 kf = *(const f16x8*)&KS[cur][keyrow[kc]*64 + (((ks*4 + quad) ^ gk[kc])*8)];
                sc[0][kc] = __builtin_amdgcn_mfma_f32_16x16x32_f16(kf, qf[0][ks], sc[0][kc], 0,0,0);
                sc[1][kc] = __builtin_amdgcn_mfma_f32_16x16x32_f16(kf, qf[1][ks], sc[1][kc], 0,0,0);
            }
        }

        // ---- p = exp2(s), pack to x32 B-fragments (k = 8*quad + j)
        union { f16x2 h2[4]; f16x8 h8; } ph[2][2];
        #pragma unroll
        for (int qt = 0; qt < 2; ++qt) {
            #pragma unroll
            for (int kg = 0; kg < 2; ++kg) {
                float e0 = exp2f(sc[qt][2*kg][0]), e1 = exp2f(sc[qt][2*kg][1]);
                float e2 = exp2f(sc[qt][2*kg][2]), e3 = exp2f(sc[qt][2*kg][3]);
                float e4 = exp2f(sc[qt][2*kg+1][0]), e5 = exp2f(sc[qt][2*kg+1][1]);
                float e6 = exp2f(sc[qt][2*kg+1][2]), e7 = exp2f(sc[qt][2*kg+1][3]);
                ph[qt][kg].h2[0] = pkrtz(e0, e1);
                ph[qt][kg].h2[1] = pkrtz(e2, e3);
                ph[qt][kg].h2[2] = pkrtz(e4, e5);
                ph[qt][kg].h2[3] = pkrtz(e6, e7);
            }
        }

        // ---- lsum via indicator-row MFMA (V^T row 64; tail keys -> 0)
        #pragma unroll
        for (int kg = 0; kg < 2; ++kg) {
            f16x8 of = *(const f16x8*)&VS[cur][rowo*64 + (((kg*4 + quad) ^ go)*8)];
            lsacc[0] = __builtin_amdgcn_mfma_f32_16x16x32_f16(of, ph[0][kg].h8, lsacc[0], 0,0,0);
            lsacc[1] = __builtin_amdgcn_mfma_f32_16x16x32_f16(of, ph[1][kg].h8, lsacc[1], 0,0,0);
        }

        // ---- PV: O^T += V^T·P^T (zero tail columns keep O exact)
        #pragma unroll
        for (int dc = 0; dc < 4; ++dc) {
            const int d = dc*16 + col;
            const int gd = swz(d);
            #pragma unroll
            for (int kg = 0; kg < 2; ++kg) {
                f16x8 vf = *(const f16x8*)&VS[cur][d*64 + (((kg*4 + quad) ^ gd)*8)];
                oacc[0][dc] = __builtin_amdgcn_mfma_f32_16x16x32_f16(vf, ph[0][kg].h8, oacc[0][dc], 0,0,0);
                oacc[1][dc] = __builtin_amdgcn_mfma_f32_16x16x32_f16(vf, ph[1][kg].h8, oacc[1][dc], 0,0,0);
            }
        }
    }

    // lsum lives in D row 0 of lsacc = lanes 0..15, element 0 (q = qt*16+lane)
    float inv[2];
    #pragma unroll
    for (int qt = 0; qt < 2; ++qt) {
        float lv = __shfl(lsacc[qt][0], col, 64);
        inv[qt] = 1.0f / lv;
    }
    #pragma unroll
    for (int qt = 0; qt < 2; ++qt) {
        const int q = q0 + qt*16 + col;
        f16* op = &O[((size_t)b*Sz + q)*Ez + h*Dz];
        #pragma unroll
        for (int dc = 0; dc < 4; ++dc) {
            f16 ov[4] = {(f16)(oacc[qt][dc][0]*inv[qt]), (f16)(oacc[qt][dc][1]*inv[qt]),
                         (f16)(oacc[qt][dc][2]*inv[qt]), (f16)(oacc[qt][dc][3]*inv[qt])};
            *(uint2*)&op[dc*16 + quad*4] = *(uint2*)ov;
        }
    }
}

// ===========================================================================
extern "C" void kernel_launch(void* const* d_in, const int* in_sizes, int n_in,
                              void* d_out, int out_size, void* d_ws, size_t ws_size,
                              hipStream_t stream)
{
    const float* value = (const float*)d_in[0];
    const float* key   = (const float*)d_in[1];
    const float* query = (const float*)d_in[2];
    const int*   mask  = (const int*)d_in[3];
    const float* wq = (const float*)d_in[4];
    const float* bq = (const float*)d_in[5];
    const float* wk = (const float*)d_in[6];
    const float* bk = (const float*)d_in[7];
    const float* wv = (const float*)d_in[8];
    const float* bv = (const float*)d_in[9];
    const float* wo = (const float*)d_in[10];
    const float* bo = (const float*)d_in[11];
    float* out = (float*)d_out;

    const size_t nW   = (size_t)Ez * Ez;             // 262144
    const size_t nAct = (size_t)Bz * Sz * Ez;        // 8388608
    const size_t nVT  = (size_t)Bz * Hz * VTR * Sz;  // 10485760
    f16* wtq = (f16*)d_ws;
    f16* wtk = wtq + nW;
    f16* wtv = wtk + nW;
    f16* wto = wtv + nW;
    f16* qa  = wto + nW;
    f16* ka  = qa + nAct;
    f16* va  = ka + nAct;
    f16* qp  = va + nAct;
    f16* kp  = qp + nAct;
    f16* vp  = kp + nAct;
    f16* vt  = vp + nAct;
    f16* o16 = vt + nVT;
    int* idxp = (int*)(o16 + nAct);
    int* slenp = idxp + Bz * Sz;

    cast_kernel<<<dim3(8192, 3), 256, 0, stream>>>(query, key, value, qa, ka, va);
    prep_w<<<dim3(8, 8, 4), 256, 0, stream>>>(wq, wk, wv, wo, wtq, wtk, wtv, wto);
    mask_index<<<Bz, 256, 0, stream>>>(mask, idxp, slenp);

    proj_gemm<<<dim3(128, 4, 3), 256, 0, stream>>>(qa, ka, va, wtq, wtk, wtv,
                                                   bq, bk, bv, qp, kp, vp);

    compact_v<<<dim3(32, Hz, Bz), 256, 0, stream>>>(vp, idxp, slenp, vt);

    attn_f16<<<1024, 256, 0, stream>>>(qp, kp, vt, idxp, slenp, o16);

    out_gemm<<<dim3(128, 8), 256, 0, stream>>>(o16, wto, bo, out);
}

// Round 9
// 290.935 us; speedup vs baseline: 1.0350x; 1.0350x over previous
//
#include <hip/hip_runtime.h>

#define Bz 8
#define Sz 2048
#define Ez 512
#define Hz 8
#define Dz 64

typedef _Float16 f16;
typedef __attribute__((ext_vector_type(2))) _Float16 f16x2;
typedef __attribute__((ext_vector_type(8))) _Float16 f16x8;
typedef __attribute__((ext_vector_type(4))) float f32x4;

#define LOG2E 1.44269504f

__device__ __forceinline__ void async16(const void* g, void* l) {
    __builtin_amdgcn_global_load_lds(
        (const __attribute__((address_space(1))) unsigned int*)g,
        (__attribute__((address_space(3))) unsigned int*)l, 16, 0, 0);
}

__device__ __forceinline__ f16x2 pkrtz(float a, float b) {
    return __builtin_bit_cast(f16x2, __builtin_amdgcn_cvt_pkrtz(a, b));
}

__device__ __forceinline__ int swz(int row) {
    return (row & 7) ^ ((2 * ((row >> 3) & 3)) & 7);
}

// ===========================================================================
// cast: z<3 -> fp32 activations -> f16 (q/k/v); z==3 (blocks 0..7) -> mask
// compaction: idx[b][.] = unmasked key list (ascending), slen[b] = count.
// ===========================================================================
__global__ __launch_bounds__(256)
void cast_kernel(const float* __restrict__ q, const float* __restrict__ k,
                 const float* __restrict__ v, const int* __restrict__ mask,
                 f16* __restrict__ qa, f16* __restrict__ ka, f16* __restrict__ va,
                 int* __restrict__ idx, int* __restrict__ slen)
{
    const int z = blockIdx.y;
    const int tid = threadIdx.x;
    if (z == 3) {
        const int b = blockIdx.x;
        if (b >= Bz) return;
        __shared__ int sc2[2][256];
        __shared__ int stot;
        const int* mp = mask + (size_t)b * Sz;
        int m[8], c = 0;
        #pragma unroll
        for (int j = 0; j < 8; ++j) { m[j] = mp[tid*8 + j]; c += (m[j] == 0); }
        sc2[0][tid] = c;
        __syncthreads();
        int src = 0;
        #pragma unroll
        for (int s = 1; s < 256; s <<= 1) {
            int vv = sc2[src][tid] + ((tid >= s) ? sc2[src][tid - s] : 0);
            sc2[src ^ 1][tid] = vv;
            src ^= 1;
            __syncthreads();
        }
        int incl = sc2[src][tid];
        int base = incl - c;
        if (tid == 255) { slen[b] = incl; stot = incl; }
        int kk = base;
        #pragma unroll
        for (int j = 0; j < 8; ++j)
            if (m[j] == 0) idx[(size_t)b * Sz + (kk++)] = tid*8 + j;
        __syncthreads();
        for (int j = stot + tid; j < Sz; j += 256) idx[(size_t)b * Sz + j] = 0;
        return;
    }
    const int i = blockIdx.x * 256 + tid;
    const float* src = (z == 0) ? q : (z == 1) ? k : v;
    f16* dst = (z == 0) ? qa : (z == 1) ? ka : va;
    float4 x = *(const float4*)&src[(size_t)i * 4];
    f16x2 h0 = pkrtz(x.x, x.y), h1 = pkrtz(x.z, x.w);
    f16 h[4] = {h0[0], h0[1], h1[0], h1[1]};
    *(uint2*)&dst[(size_t)i * 4] = *(uint2*)h;
}

// ===========================================================================
// prep_w: W fp32 [k][n] -> Wt f16 [n][k]; z==0 (wq) scaled by 0.125*log2e
// ===========================================================================
__global__ __launch_bounds__(256)
void prep_w(const float* __restrict__ W0, const float* __restrict__ W1,
            const float* __restrict__ W2, const float* __restrict__ W3,
            f16* __restrict__ T0, f16* __restrict__ T1,
            f16* __restrict__ T2, f16* __restrict__ T3)
{
    __shared__ float S[64][68];
    const float* W = (blockIdx.z==0)?W0:(blockIdx.z==1)?W1:(blockIdx.z==2)?W2:W3;
    f16*         T = (blockIdx.z==0)?T0:(blockIdx.z==1)?T1:(blockIdx.z==2)?T2:T3;
    const float sc = (blockIdx.z == 0) ? 0.125f * LOG2E : 1.0f;
    const int k0 = blockIdx.x * 64, n0 = blockIdx.y * 64;
    const int tid = threadIdx.x;
    {
        int kr = tid >> 4, nc = (tid & 15) * 4;
        #pragma unroll
        for (int i = 0; i < 4; ++i) {
            float4 w4 = *(const float4*)&W[(size_t)(k0 + kr + i*16) * Ez + n0 + nc];
            S[kr + i*16][nc+0] = w4.x; S[kr + i*16][nc+1] = w4.y;
            S[kr + i*16][nc+2] = w4.z; S[kr + i*16][nc+3] = w4.w;
        }
    }
    __syncthreads();
    {
        int n = tid >> 2, kq = tid & 3;
        f16 h[16];
        #pragma unroll
        for (int j = 0; j < 16; ++j) h[j] = (f16)(S[kq*16 + j][n] * sc);
        f16* dst = &T[(size_t)(n0 + n) * Ez + k0 + kq*16];
        *(uint4*)&dst[0] = *(uint4*)&h[0];
        *(uint4*)&dst[8] = *(uint4*)&h[8];
    }
}

// ===========================================================================
// compact_v: gather unmasked V rows from (B,H,S,D), transpose to (B,H,D,Sz)
// compacted along s with zero fill to the tile boundary.
// ===========================================================================
__global__ __launch_bounds__(256)
void compact_v(const f16* __restrict__ vp, const int* __restrict__ idx,
               const int* __restrict__ slen, f16* __restrict__ vt)
{
    const int ct = blockIdx.x, h = blockIdx.y, b = blockIdx.z;
    const int sl = slen[b];
    if (ct * 64 >= sl && !(ct == 0 && sl == 0)) return;
    __shared__ f16 S[64 * 72];
    const int tid = threadIdx.x;
    {
        int r = tid >> 2, ch = tid & 3;
        int j = ct * 64 + r;
        uint4 v0 = {0,0,0,0}, v1 = {0,0,0,0};
        if (j < sl) {
            int s = idx[(size_t)b * Sz + j];
            const f16* srcp = vp + (((size_t)b * Hz + h) * Sz + s) * Dz + ch * 16;
            v0 = *(const uint4*)&srcp[0];
            v1 = *(const uint4*)&srcp[8];
        }
        *(uint4*)&S[r*72 + ch*16]     = v0;
        *(uint4*)&S[r*72 + ch*16 + 8] = v1;
    }
    __syncthreads();
    {
        int d = tid >> 2, kq = tid & 3;
        f16 hh[16];
        #pragma unroll
        for (int j = 0; j < 16; ++j) hh[j] = S[(kq*16 + j)*72 + d];
        f16* dst = vt + (((size_t)b * Hz + h) * Dz + d) * Sz + ct*64 + kq*16;
        *(uint4*)&dst[0] = *(uint4*)&hh[0];
        *(uint4*)&dst[8] = *(uint4*)&hh[8];
    }
}

// ===========================================================================
// proj_gemm: DOUBLE-buffered DMA staging, 128x128 tile, BK=32.
// z picks {q,k,v}. Epilogue: two-pass LDS reorder, f16 scatter (B,H,S,D).
// ===========================================================================
__global__ __launch_bounds__(256, 4)
void proj_gemm(const f16* __restrict__ qa, const f16* __restrict__ ka,
               const f16* __restrict__ va,
               const f16* __restrict__ wtq, const f16* __restrict__ wtk,
               const f16* __restrict__ wtv,
               const float* __restrict__ bqp, const float* __restrict__ bkp,
               const float* __restrict__ bvp,
               f16* __restrict__ qp, f16* __restrict__ kp, f16* __restrict__ vp)
{
    __shared__ __align__(16) char lds[32768];
    const int z = blockIdx.z;
    const f16* A  = (z==0)?qa:(z==1)?ka:va;
    const f16* Wt = (z==0)?wtq:(z==1)?wtk:wtv;
    const float* bias = (z==0)?bqp:(z==1)?bkp:bvp;
    f16* C16 = (z==0)?qp:(z==1)?kp:vp;
    const float bscale = (z==0) ? 0.125f*LOG2E : 1.0f;

    const int tid  = threadIdx.x;
    const int lane = tid & 63, w = tid >> 6;
    const int col  = lane & 15, quad = lane >> 4;
    const int wm = w & 1, wn = w >> 1;
    const int m0 = blockIdx.x * 128, n0 = blockIdx.y * 128;
    const int srow = lane >> 2, schunk = lane & 3;

    f32x4 acc[4][4];
    #pragma unroll
    for (int i = 0; i < 4; ++i)
        #pragma unroll
        for (int j = 0; j < 4; ++j) acc[i][j] = (f32x4){0.f,0.f,0.f,0.f};

    auto issue = [&](int t, int buf) {
        f16* As = (f16*)(lds + buf * 16384);
        f16* Ws = As + 4096;
        #pragma unroll
        for (int i = 0; i < 2; ++i) {
            int row = w*32 + i*16 + srow;
            int cl = schunk ^ ((row >> 1) & 3);
            async16(&A[(size_t)(m0 + row) * Ez + t*32 + cl*8],  &As[row*32 + schunk*8]);
            async16(&Wt[(size_t)(n0 + row) * Ez + t*32 + cl*8], &Ws[row*32 + schunk*8]);
        }
    };

    issue(0, 0);
    const int xrc = (col >> 1) & 3;

    for (int t = 0; t < 16; ++t) {
        const int cur = t & 1;
        __syncthreads();
        if (t < 15) issue(t + 1, cur ^ 1);
        f16* As = (f16*)(lds + cur * 16384);
        f16* Ws = As + 4096;
        f16x8 af[4];
        #pragma unroll
        for (int mi = 0; mi < 4; ++mi)
            af[mi] = *(const f16x8*)&As[(wm*64 + mi*16 + col)*32 + ((quad ^ xrc)*8)];
        #pragma unroll
        for (int ni = 0; ni < 4; ++ni) {
            f16x8 wf = *(const f16x8*)&Ws[(wn*64 + ni*16 + col)*32 + ((quad ^ xrc)*8)];
            #pragma unroll
            for (int mi = 0; mi < 4; ++mi)
                acc[mi][ni] = __builtin_amdgcn_mfma_f32_16x16x32_f16(af[mi], wf, acc[mi][ni], 0,0,0);
        }
    }

    f16* Tr = (f16*)lds;     // [128][72]
    #pragma unroll
    for (int p = 0; p < 2; ++p) {
        __syncthreads();
        if (wn == p) {
            #pragma unroll
            for (int ni = 0; ni < 4; ++ni) {
                float bv = bias[n0 + p*64 + ni*16 + col] * bscale;
                #pragma unroll
                for (int mi = 0; mi < 4; ++mi)
                    #pragma unroll
                    for (int rr = 0; rr < 4; ++rr) {
                        int ml = wm*64 + mi*16 + quad*4 + rr;
                        Tr[ml*72 + ni*16 + col] = (f16)(acc[mi][ni][rr] + bv);
                    }
            }
        }
        __syncthreads();
        int rw = tid >> 1, half = tid & 1;
        int m = m0 + rw, b = m >> 11, s = m & (Sz-1);
        int hh = (n0 >> 6) + p;
        f16* dst = &C16[(((size_t)b*Hz + hh)*Sz + s)*Dz + half*32];
        const f16* srcp = &Tr[rw*72 + half*32];
        #pragma unroll
        for (int j = 0; j < 4; ++j)
            *(uint4*)&dst[j*8] = *(const uint4*)&srcp[j*8];
    }
}

// ===========================================================================
// out_gemm: DOUBLE-buffered staging, 128x128 tile, fp32 row-major + bias.
// ===========================================================================
__global__ __launch_bounds__(256, 4)
void out_gemm(const f16* __restrict__ A, const f16* __restrict__ Wt,
              const float* __restrict__ bias, float* __restrict__ Cf)
{
    __shared__ __align__(16) char lds[32768];
    const int tid  = threadIdx.x;
    const int lane = tid & 63, w = tid >> 6;
    const int col  = lane & 15, quad = lane >> 4;
    const int wm = w & 1, wn = w >> 1;
    const int m0 = blockIdx.x * 128, n0 = blockIdx.y * 128;
    const int srow = lane >> 2, schunk = lane & 3;

    f32x4 acc[4][4];
    #pragma unroll
    for (int i = 0; i < 4; ++i)
        #pragma unroll
        for (int j = 0; j < 4; ++j) acc[i][j] = (f32x4){0.f,0.f,0.f,0.f};

    auto issue = [&](int t, int buf) {
        f16* As = (f16*)(lds + buf * 16384);
        f16* Ws = As + 4096;
        #pragma unroll
        for (int i = 0; i < 2; ++i) {
            int row = w*32 + i*16 + srow;
            int cl = schunk ^ ((row >> 1) & 3);
            async16(&A[(size_t)(m0 + row) * Ez + t*32 + cl*8],  &As[row*32 + schunk*8]);
            async16(&Wt[(size_t)(n0 + row) * Ez + t*32 + cl*8], &Ws[row*32 + schunk*8]);
        }
    };

    issue(0, 0);
    const int xrc = (col >> 1) & 3;

    for (int t = 0; t < 16; ++t) {
        const int cur = t & 1;
        __syncthreads();
        if (t < 15) issue(t + 1, cur ^ 1);
        f16* As = (f16*)(lds + cur * 16384);
        f16* Ws = As + 4096;
        f16x8 af[4];
        #pragma unroll
        for (int mi = 0; mi < 4; ++mi)
            af[mi] = *(const f16x8*)&As[(wm*64 + mi*16 + col)*32 + ((quad ^ xrc)*8)];
        #pragma unroll
        for (int ni = 0; ni < 4; ++ni) {
            f16x8 wf = *(const f16x8*)&Ws[(wn*64 + ni*16 + col)*32 + ((quad ^ xrc)*8)];
            #pragma unroll
            for (int mi = 0; mi < 4; ++mi)
                acc[mi][ni] = __builtin_amdgcn_mfma_f32_16x16x32_f16(af[mi], wf, acc[mi][ni], 0,0,0);
        }
    }

    #pragma unroll
    for (int ni = 0; ni < 4; ++ni) {
        int n = n0 + wn*64 + ni*16 + col;
        float bv = bias[n];
        #pragma unroll
        for (int mi = 0; mi < 4; ++mi)
            #pragma unroll
            for (int rr = 0; rr < 4; ++rr) {
                int m = m0 + wm*64 + mi*16 + quad*4 + rr;
                Cf[(size_t)m * Ez + n] = acc[mi][ni][rr] + bv;
            }
    }
}

// ===========================================================================
// Flash attention over compacted keys (R7 softmax scheme + zero-C MFMA init).
// ===========================================================================
__global__ __launch_bounds__(256, 4)
void attn_f16(const f16* __restrict__ Q, const f16* __restrict__ K,
              const f16* __restrict__ VT, const int* __restrict__ idx,
              const int* __restrict__ slen, f16* __restrict__ O)
{
    __shared__ __align__(16) f16 KS[2][64*64];
    __shared__ __align__(16) f16 VS[2][64*64];

    const int tid  = threadIdx.x;
    const int lane = tid & 63, w = tid >> 6;
    const int col  = lane & 15, quad = lane >> 4;

    const int blk = blockIdx.x;
    const int xcd = blk & 7, slot = blk >> 3;
    const int bh = xcd + 8 * (slot >> 4);
    const int qb = slot & 15;
    const int b = bh >> 3, h = bh & 7;

    const int sl = slen[b];
    int nt = (sl + 63) >> 6;
    if (nt < 1) nt = 1;

    const int q0 = qb * 128 + w * 32;

    f16x8 qf[2][2];
    #pragma unroll
    for (int qt = 0; qt < 2; ++qt)
        #pragma unroll
        for (int ks = 0; ks < 2; ++ks)
            qf[qt][ks] = *(const f16x8*)&Q[((size_t)bh*Sz + q0 + qt*16 + col)*Dz + ks*32 + quad*8];

    const f16* Kp = K + (size_t)bh * Sz * Dz;
    const f16* Vp = VT + (size_t)bh * Dz * Sz;
    const int* ixp = idx + (size_t)b * Sz;

    const int srow = lane >> 3, sch = lane & 7;
    const int row0 = w*16 + srow, row1 = row0 + 8;
    const int cl0 = sch ^ swz(row0), cl1 = sch ^ swz(row1);

    int keyrow[4], gk[4];
    #pragma unroll
    for (int kc = 0; kc < 4; ++kc) {
        keyrow[kc] = 32*(kc>>1) + 8*(col>>2) + 4*(kc&1) + (col&3);
        gk[kc] = swz(keyrow[kc]);
    }

    f32x4 oacc[2][4];
    #pragma unroll
    for (int qt = 0; qt < 2; ++qt)
        #pragma unroll
        for (int dc = 0; dc < 4; ++dc) oacc[qt][dc] = (f32x4){0.f,0.f,0.f,0.f};
    float lsum[2] = {0.f, 0.f};
    const f32x4 zero4 = (f32x4){0.f, 0.f, 0.f, 0.f};

    auto issue = [&](int t, int buf, int s0, int s1) {
        async16(&Kp[(size_t)s0*Dz + cl0*8],          &KS[buf][row0*64 + sch*8]);
        async16(&Vp[(size_t)row0*Sz + t*64 + cl0*8], &VS[buf][row0*64 + sch*8]);
        async16(&Kp[(size_t)s1*Dz + cl1*8],          &KS[buf][row1*64 + sch*8]);
        async16(&Vp[(size_t)row1*Sz + t*64 + cl1*8], &VS[buf][row1*64 + sch*8]);
    };

    int cs0 = ixp[row0], cs1 = ixp[row1];
    issue(0, 0, cs0, cs1);
    int ns0 = 0, ns1 = 0;
    if (nt > 1) { ns0 = ixp[64 + row0]; ns1 = ixp[64 + row1]; }

    for (int t = 0; t < nt; ++t) {
        const int cur = t & 1;
        __syncthreads();
        if (t + 1 < nt) {
            issue(t + 1, cur ^ 1, ns0, ns1);
            if (t + 2 < nt) {
                ns0 = ixp[(t+2)*64 + row0];
                ns1 = ixp[(t+2)*64 + row1];
            }
        }

        // ---- QK^T: S^T = K·Q^T (C initialized from persistent zero regs)
        f32x4 sc[2][4];
        #pragma unroll
        for (int kc = 0; kc < 4; ++kc) {
            f16x8 kf0 = *(const f16x8*)&KS[cur][keyrow[kc]*64 + ((quad ^ gk[kc])*8)];
            f16x8 kf1 = *(const f16x8*)&KS[cur][keyrow[kc]*64 + (((4 + quad) ^ gk[kc])*8)];
            sc[0][kc] = __builtin_amdgcn_mfma_f32_16x16x32_f16(kf0, qf[0][0], zero4, 0,0,0);
            sc[1][kc] = __builtin_amdgcn_mfma_f32_16x16x32_f16(kf0, qf[1][0], zero4, 0,0,0);
            sc[0][kc] = __builtin_amdgcn_mfma_f32_16x16x32_f16(kf1, qf[0][1], sc[0][kc], 0,0,0);
            sc[1][kc] = __builtin_amdgcn_mfma_f32_16x16x32_f16(kf1, qf[1][1], sc[1][kc], 0,0,0);
        }

        // ---- p = exp2(s); lsum (predicated on last tile); pack x32 B-frags
        const bool last = (t == nt - 1);
        union { f16x2 h2[4]; f16x8 h8; } ph[2][2];
        #pragma unroll
        for (int qt = 0; qt < 2; ++qt) {
            #pragma unroll
            for (int kg = 0; kg < 2; ++kg) {
                float e0 = exp2f(sc[qt][2*kg][0]), e1 = exp2f(sc[qt][2*kg][1]);
                float e2 = exp2f(sc[qt][2*kg][2]), e3 = exp2f(sc[qt][2*kg][3]);
                float e4 = exp2f(sc[qt][2*kg+1][0]), e5 = exp2f(sc[qt][2*kg+1][1]);
                float e6 = exp2f(sc[qt][2*kg+1][2]), e7 = exp2f(sc[qt][2*kg+1][3]);
                float ls;
                if (last) {
                    int rem = sl - t*64 - 32*kg - 8*quad;
                    ls = ((rem > 0 ? e0 : 0.f) + (rem > 1 ? e1 : 0.f))
                       + ((rem > 2 ? e2 : 0.f) + (rem > 3 ? e3 : 0.f))
                       + ((rem > 4 ? e4 : 0.f) + (rem > 5 ? e5 : 0.f))
                       + ((rem > 6 ? e6 : 0.f) + (rem > 7 ? e7 : 0.f));
                } else {
                    ls = ((e0 + e1) + (e2 + e3)) + ((e4 + e5) + (e6 + e7));
                }
                lsum[qt] += ls;
                ph[qt][kg].h2[0] = pkrtz(e0, e1);
                ph[qt][kg].h2[1] = pkrtz(e2, e3);
                ph[qt][kg].h2[2] = pkrtz(e4, e5);
                ph[qt][kg].h2[3] = pkrtz(e6, e7);
            }
        }

        // ---- PV: O^T += V^T·P^T (zero tail columns keep O exact)
        #pragma unroll
        for (int dc = 0; dc < 4; ++dc) {
            const int d = dc*16 + col;
            const int gd = swz(d);
            #pragma unroll
            for (int kg = 0; kg < 2; ++kg) {
                f16x8 vf = *(const f16x8*)&VS[cur][d*64 + (((kg*4 + quad) ^ gd)*8)];
                oacc[0][dc] = __builtin_amdgcn_mfma_f32_16x16x32_f16(vf, ph[0][kg].h8, oacc[0][dc], 0,0,0);
                oacc[1][dc] = __builtin_amdgcn_mfma_f32_16x16x32_f16(vf, ph[1][kg].h8, oacc[1][dc], 0,0,0);
            }
        }
    }

    float inv[2];
    #pragma unroll
    for (int qt = 0; qt < 2; ++qt) {
        float v = lsum[qt];
        v += __shfl_xor(v, 16, 64);
        v += __shfl_xor(v, 32, 64);
        inv[qt] = 1.0f / v;
    }
    #pragma unroll
    for (int qt = 0; qt < 2; ++qt) {
        const int q = q0 + qt*16 + col;
        f16* op = &O[((size_t)b*Sz + q)*Ez + h*Dz];
        #pragma unroll
        for (int dc = 0; dc < 4; ++dc) {
            f16 ov[4] = {(f16)(oacc[qt][dc][0]*inv[qt]), (f16)(oacc[qt][dc][1]*inv[qt]),
                         (f16)(oacc[qt][dc][2]*inv[qt]), (f16)(oacc[qt][dc][3]*inv[qt])};
            *(uint2*)&op[dc*16 + quad*4] = *(uint2*)ov;
        }
    }
}

// ===========================================================================
extern "C" void kernel_launch(void* const* d_in, const int* in_sizes, int n_in,
                              void* d_out, int out_size, void* d_ws, size_t ws_size,
                              hipStream_t stream)
{
    const float* value = (const float*)d_in[0];
    const float* key   = (const float*)d_in[1];
    const float* query = (const float*)d_in[2];
    const int*   mask  = (const int*)d_in[3];
    const float* wq = (const float*)d_in[4];
    const float* bq = (const float*)d_in[5];
    const float* wk = (const float*)d_in[6];
    const float* bk = (const float*)d_in[7];
    const float* wv = (const float*)d_in[8];
    const float* bv = (const float*)d_in[9];
    const float* wo = (const float*)d_in[10];
    const float* bo = (const float*)d_in[11];
    float* out = (float*)d_out;

    const size_t nW   = (size_t)Ez * Ez;             // 262144
    const size_t nAct = (size_t)Bz * Sz * Ez;        // 8388608
    f16* wtq = (f16*)d_ws;
    f16* wtk = wtq + nW;
    f16* wtv = wtk + nW;
    f16* wto = wtv + nW;
    f16* qa  = wto + nW;
    f16* ka  = qa + nAct;
    f16* va  = ka + nAct;
    f16* qp  = va + nAct;
    f16* kp  = qp + nAct;
    f16* vp  = kp + nAct;
    f16* vt  = vp + nAct;
    f16* o16 = vt + nAct;
    int* idxp = (int*)(o16 + nAct);
    int* slenp = idxp + Bz * Sz;

    cast_kernel<<<dim3(8192, 4), 256, 0, stream>>>(query, key, value, mask,
                                                   qa, ka, va, idxp, slenp);
    prep_w<<<dim3(8, 8, 4), 256, 0, stream>>>(wq, wk, wv, wo, wtq, wtk, wtv, wto);

    proj_gemm<<<dim3(128, 4, 3), 256, 0, stream>>>(qa, ka, va, wtq, wtk, wtv,
                                                   bq, bk, bv, qp, kp, vp);

    compact_v<<<dim3(32, Hz, Bz), 256, 0, stream>>>(vp, idxp, slenp, vt);

    attn_f16<<<1024, 256, 0, stream>>>(qp, kp, vt, idxp, slenp, o16);

    out_gemm<<<dim3(128, 4), 256, 0, stream>>>(o16, wto, bo, out);
}